// Round 3
// baseline (748.977 us; speedup 1.0000x reference)
//
#include <hip/hip_runtime.h>
#include <hip/hip_bf16.h>
#include <cstdint>
#include <cstddef>
#include <math.h>

#define NEG_SLOPE 0.2f

__device__ __forceinline__ float lrelu(float x) { return x > 0.f ? x : NEG_SLOPE * x; }

// xw is stored SLICE-MAJOR: xw_s[slice][n][16], slice = ch>>4 (8 slices of 16 ch).
// Rationale: pass k_agg pins slice s to XCD s (blockIdx%8), so each XCD's gather
// working set is 50000*64B = 3.2 MB < 4 MB per-XCD L2.

// ---------------- GEMM: xw = x @ W1^T, written slice-major ----------------
__global__ __launch_bounds__(256) void k_gemm1(const float* __restrict__ x,
                                               const float* __restrict__ W1,
                                               float* __restrict__ xw, int N)
{
    __shared__ float As[64][33];
    __shared__ float Bs[128][33];
    const int tid = threadIdx.x;
    const int tx = tid & 31, ty = tid >> 5;
    const int bm = blockIdx.x * 64;
    float acc[8][4];
    #pragma unroll
    for (int i = 0; i < 8; i++)
        #pragma unroll
        for (int j = 0; j < 4; j++) acc[i][j] = 0.f;

    for (int k0 = 0; k0 < 128; k0 += 32) {
        #pragma unroll
        for (int t = tid; t < 512; t += 256) {
            int r = t >> 3, q = t & 7;
            int n = bm + r;
            float4 f = make_float4(0.f, 0.f, 0.f, 0.f);
            if (n < N) f = *(const float4*)(x + (size_t)n * 128 + k0 + 4 * q);
            As[r][4*q+0] = f.x; As[r][4*q+1] = f.y; As[r][4*q+2] = f.z; As[r][4*q+3] = f.w;
        }
        #pragma unroll
        for (int t = tid; t < 1024; t += 256) {
            int c = t >> 3, q = t & 7;
            float4 f = *(const float4*)(W1 + (size_t)c * 128 + k0 + 4 * q);
            Bs[c][4*q+0] = f.x; Bs[c][4*q+1] = f.y; Bs[c][4*q+2] = f.z; Bs[c][4*q+3] = f.w;
        }
        __syncthreads();
        #pragma unroll 4
        for (int kk = 0; kk < 32; kk++) {
            float a[8], b[4];
            #pragma unroll
            for (int i = 0; i < 8; i++) a[i] = As[ty * 8 + i][kk];
            #pragma unroll
            for (int j = 0; j < 4; j++) b[j] = Bs[tx + 32 * j][kk];
            #pragma unroll
            for (int i = 0; i < 8; i++)
                #pragma unroll
                for (int j = 0; j < 4; j++) acc[i][j] = fmaf(a[i], b[j], acc[i][j]);
        }
        __syncthreads();
    }
    #pragma unroll
    for (int i = 0; i < 8; i++) {
        int n = bm + ty * 8 + i;
        if (n < N) {
            #pragma unroll
            for (int j = 0; j < 4; j++) {
                int ch = tx + 32 * j;
                xw[((size_t)(ch >> 4) * N + n) * 16 + (ch & 15)] = acc[i][j];
            }
        }
    }
}

// ---------------- per-node attention logits a_src/a_dst [N][4] ----------------
__global__ __launch_bounds__(256) void k_att1(const float* __restrict__ xw,
                                              const float* __restrict__ att_src,
                                              const float* __restrict__ att_dst,
                                              float* __restrict__ a_src,
                                              float* __restrict__ a_dst, int N)
{
    int wave = (blockIdx.x * blockDim.x + threadIdx.x) >> 6;
    int lane = threadIdx.x & 63;
    if (wave >= N) return;
    int ch0 = lane, ch1 = 64 + lane;
    float v0 = xw[((size_t)(ch0 >> 4) * N + wave) * 16 + (ch0 & 15)];
    float v1 = xw[((size_t)(ch1 >> 4) * N + wave) * 16 + (ch1 & 15)];
    float s0 = v0 * att_src[ch0], s1 = v1 * att_src[ch1];
    float d0 = v0 * att_dst[ch0], d1 = v1 * att_dst[ch1];
    #pragma unroll
    for (int off = 16; off; off >>= 1) {
        s0 += __shfl_xor(s0, off); s1 += __shfl_xor(s1, off);
        d0 += __shfl_xor(d0, off); d1 += __shfl_xor(d1, off);
    }
    if ((lane & 31) == 0) {
        int h = lane >> 5;
        a_src[wave * 4 + h]     = s0;
        a_src[wave * 4 + 2 + h] = s1;
        a_dst[wave * 4 + h]     = d0;
        a_dst[wave * 4 + 2 + h] = d1;
    }
}

// ---------------- CSR build ----------------
__global__ void k_count(const int* __restrict__ ei, int E, int N, int* __restrict__ deg)
{
    int e = blockIdx.x * blockDim.x + threadIdx.x;
    if (e >= E + N) return;
    int d = (e < E) ? ei[(size_t)E + e] : (e - E);
    atomicAdd(&deg[d], 1);
}

// wave-shuffle scan: 4096 elems/chunk, ~4 barriers/chunk (vs 20 in the ladder scan)
__global__ __launch_bounds__(1024) void k_scan(const int* __restrict__ deg,
                                               int* __restrict__ row_ptr,
                                               int* __restrict__ cursor, int N)
{
    __shared__ int wtot[16];
    __shared__ int s_carry;
    const int tid = threadIdx.x;
    const int w = tid >> 6, lane = tid & 63;
    if (tid == 0) s_carry = 0;
    __syncthreads();
    for (int base = 0; base < N; base += 4096) {
        int idx = base + tid * 4;
        int v0 = (idx     < N) ? deg[idx]     : 0;
        int v1 = (idx + 1 < N) ? deg[idx + 1] : 0;
        int v2 = (idx + 2 < N) ? deg[idx + 2] : 0;
        int v3 = (idx + 3 < N) ? deg[idx + 3] : 0;
        int tsum = v0 + v1 + v2 + v3;
        int v = tsum;
        #pragma unroll
        for (int off = 1; off < 64; off <<= 1) {
            int u = __shfl_up(v, off);
            if (lane >= off) v += u;
        }
        if (lane == 63) wtot[w] = v;
        __syncthreads();
        int carry = s_carry;
        if (w == 0) {
            int t = (lane < 16) ? wtot[lane] : 0;
            #pragma unroll
            for (int off = 1; off < 16; off <<= 1) {
                int u = __shfl_up(t, off);
                if (lane >= off) t += u;
            }
            if (lane < 16) wtot[lane] = t;
        }
        __syncthreads();
        int woff = (w > 0) ? wtot[w - 1] : 0;
        int excl = carry + woff + (v - tsum);
        if (idx     < N) { row_ptr[idx]     = excl; cursor[idx]     = excl; } excl += v0;
        if (idx + 1 < N) { row_ptr[idx + 1] = excl; cursor[idx + 1] = excl; } excl += v1;
        if (idx + 2 < N) { row_ptr[idx + 2] = excl; cursor[idx + 2] = excl; } excl += v2;
        if (idx + 3 < N) { row_ptr[idx + 3] = excl; cursor[idx + 3] = excl; }
        __syncthreads();
        if (tid == 0) s_carry = carry + wtot[15];
        __syncthreads();
    }
    if (tid == 0) row_ptr[N] = s_carry;
}

__global__ void k_scatter(const int* __restrict__ ei, int E, int N,
                          int* __restrict__ cursor, int* __restrict__ csr_src)
{
    int e = blockIdx.x * blockDim.x + threadIdx.x;
    if (e >= E + N) return;
    int s, d;
    if (e < E) { s = ei[e]; d = ei[(size_t)E + e]; }
    else       { s = d = e - E; }
    int pos = atomicAdd(&cursor[d], 1);
    csr_src[pos] = s;
}

// ---------------- coef: per-edge normalized softmax weights [Et][4] ----------------
// One wave per dst. Fast path deg<=64: all in registers, single pass.
__global__ __launch_bounds__(256) void k_coef(const float* __restrict__ a_src,
                                              const float* __restrict__ a_dst,
                                              const int* __restrict__ row_ptr,
                                              const int* __restrict__ csr_src,
                                              float* __restrict__ coef, int N)
{
    int d = (blockIdx.x * blockDim.x + threadIdx.x) >> 6;
    int lane = threadIdx.x & 63;
    if (d >= N) return;
    float4 ad = ((const float4*)a_dst)[d];
    int beg = row_ptr[d], end = row_ptr[d + 1];
    int deg = end - beg;

    if (deg <= 64) {
        int j = beg + lane;
        bool act = j < end;
        int s = act ? csr_src[j] : 0;
        float4 as = ((const float4*)a_src)[s];
        float4 a;
        a.x = act ? lrelu(as.x + ad.x) : -INFINITY;
        a.y = act ? lrelu(as.y + ad.y) : -INFINITY;
        a.z = act ? lrelu(as.z + ad.z) : -INFINITY;
        a.w = act ? lrelu(as.w + ad.w) : -INFINITY;
        float4 mx = a;
        #pragma unroll
        for (int off = 1; off < 64; off <<= 1) {
            mx.x = fmaxf(mx.x, __shfl_xor(mx.x, off));
            mx.y = fmaxf(mx.y, __shfl_xor(mx.y, off));
            mx.z = fmaxf(mx.z, __shfl_xor(mx.z, off));
            mx.w = fmaxf(mx.w, __shfl_xor(mx.w, off));
        }
        float4 e;
        e.x = act ? __expf(a.x - mx.x) : 0.f;
        e.y = act ? __expf(a.y - mx.y) : 0.f;
        e.z = act ? __expf(a.z - mx.z) : 0.f;
        e.w = act ? __expf(a.w - mx.w) : 0.f;
        float4 sm = e;
        #pragma unroll
        for (int off = 1; off < 64; off <<= 1) {
            sm.x += __shfl_xor(sm.x, off);
            sm.y += __shfl_xor(sm.y, off);
            sm.z += __shfl_xor(sm.z, off);
            sm.w += __shfl_xor(sm.w, off);
        }
        if (act) {
            float4 c;
            c.x = e.x / (sm.x + 1e-16f);
            c.y = e.y / (sm.y + 1e-16f);
            c.z = e.z / (sm.z + 1e-16f);
            c.w = e.w / (sm.w + 1e-16f);
            ((float4*)coef)[j] = c;
        }
    } else {
        float4 mx = make_float4(-INFINITY, -INFINITY, -INFINITY, -INFINITY);
        for (int j = beg + lane; j < end; j += 64) {
            int s = csr_src[j];
            float4 as = ((const float4*)a_src)[s];
            float4 a;
            a.x = lrelu(as.x + ad.x); a.y = lrelu(as.y + ad.y);
            a.z = lrelu(as.z + ad.z); a.w = lrelu(as.w + ad.w);
            ((float4*)coef)[j] = a;                     // stage alpha
            mx.x = fmaxf(mx.x, a.x); mx.y = fmaxf(mx.y, a.y);
            mx.z = fmaxf(mx.z, a.z); mx.w = fmaxf(mx.w, a.w);
        }
        #pragma unroll
        for (int off = 1; off < 64; off <<= 1) {
            mx.x = fmaxf(mx.x, __shfl_xor(mx.x, off));
            mx.y = fmaxf(mx.y, __shfl_xor(mx.y, off));
            mx.z = fmaxf(mx.z, __shfl_xor(mx.z, off));
            mx.w = fmaxf(mx.w, __shfl_xor(mx.w, off));
        }
        float4 sm = make_float4(0.f, 0.f, 0.f, 0.f);
        for (int j = beg + lane; j < end; j += 64) {
            float4 a = ((float4*)coef)[j];
            float4 e;
            e.x = __expf(a.x - mx.x); e.y = __expf(a.y - mx.y);
            e.z = __expf(a.z - mx.z); e.w = __expf(a.w - mx.w);
            sm.x += e.x; sm.y += e.y; sm.z += e.z; sm.w += e.w;
            ((float4*)coef)[j] = e;
        }
        #pragma unroll
        for (int off = 1; off < 64; off <<= 1) {
            sm.x += __shfl_xor(sm.x, off);
            sm.y += __shfl_xor(sm.y, off);
            sm.z += __shfl_xor(sm.z, off);
            sm.w += __shfl_xor(sm.w, off);
        }
        float4 inv;
        inv.x = 1.f / (sm.x + 1e-16f); inv.y = 1.f / (sm.y + 1e-16f);
        inv.z = 1.f / (sm.z + 1e-16f); inv.w = 1.f / (sm.w + 1e-16f);
        for (int j = beg + lane; j < end; j += 64) {
            float4 e = ((float4*)coef)[j];
            e.x *= inv.x; e.y *= inv.y; e.z *= inv.z; e.w *= inv.w;
            ((float4*)coef)[j] = e;
        }
    }
}

// ---------------- agg: weighted gather, XCD-sliced by channel ----------------
// block = 256 thr = 4 waves; each wave: 4 dsts x 16 ch. slice = blockIdx%8 -> XCD.
// Fused: relu(agg+b1)*W2 partial dot, atomicAdd into xw2.
__global__ __launch_bounds__(256) void k_agg(const float* __restrict__ xw,
                                             const float* __restrict__ coef,
                                             const int* __restrict__ row_ptr,
                                             const int* __restrict__ csr_src,
                                             const float* __restrict__ b1,
                                             const float* __restrict__ W2,
                                             float* __restrict__ xw2, int N)
{
    const int slice = blockIdx.x & 7;
    const int dgrp  = blockIdx.x >> 3;
    const int wave  = threadIdx.x >> 6;
    const int lane  = threadIdx.x & 63;
    const int sub   = lane >> 4, ci = lane & 15;
    const int d     = dgrp * 16 + wave * 4 + sub;
    const int head  = slice >> 1;
    const float* xs = xw + (size_t)slice * N * 16;

    int beg = 0, end = 0;
    if (d < N) { beg = row_ptr[d]; end = row_ptr[d + 1]; }
    int deg = end - beg;
    int kmax = deg;
    kmax = max(kmax, __shfl_xor(kmax, 16));
    kmax = max(kmax, __shfl_xor(kmax, 32));

    float acc = 0.f;
    for (int k = 0; k < kmax; k++) {
        int j = beg + k;
        if (j < end) {
            int s = csr_src[j];
            float c = coef[(size_t)j * 4 + head];
            float xv = xs[(size_t)s * 16 + ci];
            acc = fmaf(c, xv, acc);
        }
    }
    if (d < N) {
        int ch = slice * 16 + ci;
        float t = fmaxf(acc + b1[ch], 0.f) * W2[ch];
        #pragma unroll
        for (int off = 1; off < 16; off <<= 1) t += __shfl_xor(t, off);
        if (ci == 0) atomicAdd(&xw2[d], t);
    }
}

// ---------------- layer 2: scalar GAT head ----------------
__global__ __launch_bounds__(256) void k_layer2(const float* __restrict__ xw2,
                                                const int* __restrict__ row_ptr,
                                                const int* __restrict__ csr_src,
                                                const float* __restrict__ att_src2,
                                                const float* __restrict__ att_dst2,
                                                const float* __restrict__ b2,
                                                float* __restrict__ out, int N)
{
    int d = (blockIdx.x * blockDim.x + threadIdx.x) >> 6;
    int lane = threadIdx.x & 63;
    if (d >= N) return;
    float as2 = att_src2[0];
    float adst = xw2[d] * att_dst2[0];
    float m = -INFINITY, l = 0.f, acc = 0.f;
    int beg = row_ptr[d], end = row_ptr[d + 1];
    for (int j = beg + lane; j < end; j += 64) {
        int s = csr_src[j];
        float xs = xw2[s];
        float al = lrelu(xs * as2 + adst);
        float nm = fmaxf(m, al);
        float sc = __expf(m - nm);
        float p = __expf(al - nm);
        l = l * sc + p;
        acc = acc * sc + p * xs;
        m = nm;
    }
    #pragma unroll
    for (int off = 32; off; off >>= 1) {
        float mo = __shfl_xor(m, off);
        float lo = __shfl_xor(l, off);
        float ao = __shfl_xor(acc, off);
        float nm = fmaxf(m, mo);
        float sa = (l  > 0.f) ? __expf(m  - nm) : 0.f;
        float sb = (lo > 0.f) ? __expf(mo - nm) : 0.f;
        l = l * sa + lo * sb;
        acc = acc * sa + ao * sb;
        m = nm;
    }
    if (lane == 0) out[d] = acc / (l + 1e-16f) + b2[0];
}

extern "C" void kernel_launch(void* const* d_in, const int* in_sizes, int n_in,
                              void* d_out, int out_size, void* d_ws, size_t ws_size,
                              hipStream_t stream)
{
    const float* x        = (const float*)d_in[0];
    const int*   ei       = (const int*)d_in[1];
    const float* W1       = (const float*)d_in[2];
    const float* att_src1 = (const float*)d_in[3];
    const float* att_dst1 = (const float*)d_in[4];
    const float* b1       = (const float*)d_in[5];
    const float* W2       = (const float*)d_in[6];
    const float* att_src2 = (const float*)d_in[7];
    const float* att_dst2 = (const float*)d_in[8];
    const float* b2       = (const float*)d_in[9];
    float* out = (float*)d_out;

    const int N  = in_sizes[0] / 128;
    const int E  = in_sizes[1] / 2;
    const int Et = E + N;

    char* p = (char*)d_ws;
    auto alloc = [&](size_t bytes) {
        char* r = p;
        p += (bytes + 255) & ~(size_t)255;
        return (void*)r;
    };
    float* xw      = (float*)alloc((size_t)N * 128 * 4);   // slice-major [8][N][16]
    float* a_src   = (float*)alloc((size_t)N * 4 * 4);
    float* a_dst   = (float*)alloc((size_t)N * 4 * 4);
    float* xw2     = (float*)alloc((size_t)N * 4);
    int*   deg     = (int*)alloc((size_t)N * 4);
    int*   row_ptr = (int*)alloc((size_t)(N + 1) * 4);
    int*   cursor  = (int*)alloc((size_t)N * 4);
    int*   csr_src = (int*)alloc((size_t)Et * 4);
    float* coef    = (float*)alloc((size_t)Et * 4 * 4);    // [Et][4] normalized

    hipMemsetAsync(deg, 0, (size_t)N * 4, stream);
    hipMemsetAsync(xw2, 0, (size_t)N * 4, stream);

    k_gemm1  <<<(N + 63) / 64,    256,  0, stream>>>(x, W1, xw, N);
    k_att1   <<<(N + 3) / 4,      256,  0, stream>>>(xw, att_src1, att_dst1, a_src, a_dst, N);
    k_count  <<<(Et + 255) / 256, 256,  0, stream>>>(ei, E, N, deg);
    k_scan   <<<1,                1024, 0, stream>>>(deg, row_ptr, cursor, N);
    k_scatter<<<(Et + 255) / 256, 256,  0, stream>>>(ei, E, N, cursor, csr_src);
    k_coef   <<<(N + 3) / 4,      256,  0, stream>>>(a_src, a_dst, row_ptr, csr_src, coef, N);
    k_agg    <<<((N + 15) / 16) * 8, 256, 0, stream>>>(xw, coef, row_ptr, csr_src,
                                                       b1, W2, xw2, N);
    k_layer2 <<<(N + 3) / 4,      256,  0, stream>>>(xw2, row_ptr, csr_src, att_src2,
                                                     att_dst2, b2, out, N);
}

// Round 4
// 622.084 us; speedup vs baseline: 1.2040x; 1.2040x over previous
//
#include <hip/hip_runtime.h>
#include <hip/hip_bf16.h>
#include <cstdint>
#include <cstddef>
#include <math.h>

#define NEG_SLOPE 0.2f

__device__ __forceinline__ float lrelu(float x) { return x > 0.f ? x : NEG_SLOPE * x; }

// xw is stored SLICE-MAJOR: xw_s[slice][n][16], slice = ch>>4 (8 slices of 16 ch).
// k_agg pins slice s to XCD s (blockIdx%8): per-XCD gather working set 3.2 MB < 4 MB L2.
// coef is HEAD-MAJOR coef_h[4][Et]: slice pass streams 6.6 MB contiguous (round-3's
// [Et][4] layout streamed 26.4 MB per pass and thrashed the xs slice out of L2).

// ---------------- GEMM: xw = x @ W1^T, written slice-major ----------------
__global__ __launch_bounds__(256) void k_gemm1(const float* __restrict__ x,
                                               const float* __restrict__ W1,
                                               float* __restrict__ xw, int N)
{
    __shared__ float As[64][33];
    __shared__ float Bs[128][33];
    const int tid = threadIdx.x;
    const int tx = tid & 31, ty = tid >> 5;
    const int bm = blockIdx.x * 64;
    float acc[8][4];
    #pragma unroll
    for (int i = 0; i < 8; i++)
        #pragma unroll
        for (int j = 0; j < 4; j++) acc[i][j] = 0.f;

    for (int k0 = 0; k0 < 128; k0 += 32) {
        #pragma unroll
        for (int t = tid; t < 512; t += 256) {
            int r = t >> 3, q = t & 7;
            int n = bm + r;
            float4 f = make_float4(0.f, 0.f, 0.f, 0.f);
            if (n < N) f = *(const float4*)(x + (size_t)n * 128 + k0 + 4 * q);
            As[r][4*q+0] = f.x; As[r][4*q+1] = f.y; As[r][4*q+2] = f.z; As[r][4*q+3] = f.w;
        }
        #pragma unroll
        for (int t = tid; t < 1024; t += 256) {
            int c = t >> 3, q = t & 7;
            float4 f = *(const float4*)(W1 + (size_t)c * 128 + k0 + 4 * q);
            Bs[c][4*q+0] = f.x; Bs[c][4*q+1] = f.y; Bs[c][4*q+2] = f.z; Bs[c][4*q+3] = f.w;
        }
        __syncthreads();
        #pragma unroll 4
        for (int kk = 0; kk < 32; kk++) {
            float a[8], b[4];
            #pragma unroll
            for (int i = 0; i < 8; i++) a[i] = As[ty * 8 + i][kk];
            #pragma unroll
            for (int j = 0; j < 4; j++) b[j] = Bs[tx + 32 * j][kk];
            #pragma unroll
            for (int i = 0; i < 8; i++)
                #pragma unroll
                for (int j = 0; j < 4; j++) acc[i][j] = fmaf(a[i], b[j], acc[i][j]);
        }
        __syncthreads();
    }
    #pragma unroll
    for (int i = 0; i < 8; i++) {
        int n = bm + ty * 8 + i;
        if (n < N) {
            #pragma unroll
            for (int j = 0; j < 4; j++) {
                int ch = tx + 32 * j;
                xw[((size_t)(ch >> 4) * N + n) * 16 + (ch & 15)] = acc[i][j];
            }
        }
    }
}

// ---------------- per-node attention logits a_src/a_dst [N][4] ----------------
__global__ __launch_bounds__(256) void k_att1(const float* __restrict__ xw,
                                              const float* __restrict__ att_src,
                                              const float* __restrict__ att_dst,
                                              float* __restrict__ a_src,
                                              float* __restrict__ a_dst, int N)
{
    int wave = (blockIdx.x * blockDim.x + threadIdx.x) >> 6;
    int lane = threadIdx.x & 63;
    if (wave >= N) return;
    int ch0 = lane, ch1 = 64 + lane;
    float v0 = xw[((size_t)(ch0 >> 4) * N + wave) * 16 + (ch0 & 15)];
    float v1 = xw[((size_t)(ch1 >> 4) * N + wave) * 16 + (ch1 & 15)];
    float s0 = v0 * att_src[ch0], s1 = v1 * att_src[ch1];
    float d0 = v0 * att_dst[ch0], d1 = v1 * att_dst[ch1];
    #pragma unroll
    for (int off = 16; off; off >>= 1) {
        s0 += __shfl_xor(s0, off); s1 += __shfl_xor(s1, off);
        d0 += __shfl_xor(d0, off); d1 += __shfl_xor(d1, off);
    }
    if ((lane & 31) == 0) {
        int h = lane >> 5;
        a_src[wave * 4 + h]     = s0;
        a_src[wave * 4 + 2 + h] = s1;
        a_dst[wave * 4 + h]     = d0;
        a_dst[wave * 4 + 2 + h] = d1;
    }
}

// ---------------- CSR build ----------------
__global__ void k_count(const int* __restrict__ ei, int E, int N, int* __restrict__ deg)
{
    int e = blockIdx.x * blockDim.x + threadIdx.x;
    if (e >= E + N) return;
    int d = (e < E) ? ei[(size_t)E + e] : (e - E);
    atomicAdd(&deg[d], 1);
}

__global__ __launch_bounds__(1024) void k_scan(const int* __restrict__ deg,
                                               int* __restrict__ row_ptr,
                                               int* __restrict__ cursor, int N)
{
    __shared__ int wtot[16];
    __shared__ int s_carry;
    const int tid = threadIdx.x;
    const int w = tid >> 6, lane = tid & 63;
    if (tid == 0) s_carry = 0;
    __syncthreads();
    for (int base = 0; base < N; base += 4096) {
        int idx = base + tid * 4;
        int v0 = (idx     < N) ? deg[idx]     : 0;
        int v1 = (idx + 1 < N) ? deg[idx + 1] : 0;
        int v2 = (idx + 2 < N) ? deg[idx + 2] : 0;
        int v3 = (idx + 3 < N) ? deg[idx + 3] : 0;
        int tsum = v0 + v1 + v2 + v3;
        int v = tsum;
        #pragma unroll
        for (int off = 1; off < 64; off <<= 1) {
            int u = __shfl_up(v, off);
            if (lane >= off) v += u;
        }
        if (lane == 63) wtot[w] = v;
        __syncthreads();
        int carry = s_carry;
        if (w == 0) {
            int t = (lane < 16) ? wtot[lane] : 0;
            #pragma unroll
            for (int off = 1; off < 16; off <<= 1) {
                int u = __shfl_up(t, off);
                if (lane >= off) t += u;
            }
            if (lane < 16) wtot[lane] = t;
        }
        __syncthreads();
        int woff = (w > 0) ? wtot[w - 1] : 0;
        int excl = carry + woff + (v - tsum);
        if (idx     < N) { row_ptr[idx]     = excl; cursor[idx]     = excl; } excl += v0;
        if (idx + 1 < N) { row_ptr[idx + 1] = excl; cursor[idx + 1] = excl; } excl += v1;
        if (idx + 2 < N) { row_ptr[idx + 2] = excl; cursor[idx + 2] = excl; } excl += v2;
        if (idx + 3 < N) { row_ptr[idx + 3] = excl; cursor[idx + 3] = excl; }
        __syncthreads();
        if (tid == 0) s_carry = carry + wtot[15];
        __syncthreads();
    }
    if (tid == 0) row_ptr[N] = s_carry;
}

__global__ void k_scatter(const int* __restrict__ ei, int E, int N,
                          int* __restrict__ cursor, int* __restrict__ csr_src)
{
    int e = blockIdx.x * blockDim.x + threadIdx.x;
    if (e >= E + N) return;
    int s, d;
    if (e < E) { s = ei[e]; d = ei[(size_t)E + e]; }
    else       { s = d = e - E; }
    int pos = atomicAdd(&cursor[d], 1);
    csr_src[pos] = s;
}

// ---------------- coef: normalized softmax weights, HEAD-MAJOR [4][Et] -----------
// No max-subtraction: |alpha| <~ 10, exp safe in fp32; normalized ratio identical.
__global__ __launch_bounds__(256) void k_coef(const float* __restrict__ a_src,
                                              const float* __restrict__ a_dst,
                                              const int* __restrict__ row_ptr,
                                              const int* __restrict__ csr_src,
                                              float* __restrict__ coef, int N, int Et)
{
    int d = (blockIdx.x * blockDim.x + threadIdx.x) >> 6;
    int lane = threadIdx.x & 63;
    if (d >= N) return;
    float4 ad = ((const float4*)a_dst)[d];
    int beg = row_ptr[d], end = row_ptr[d + 1];
    int deg = end - beg;

    if (deg <= 64) {
        int j = beg + lane;
        bool act = j < end;
        int s = act ? csr_src[j] : 0;
        float4 as = ((const float4*)a_src)[s];
        float4 e;
        e.x = act ? __expf(lrelu(as.x + ad.x)) : 0.f;
        e.y = act ? __expf(lrelu(as.y + ad.y)) : 0.f;
        e.z = act ? __expf(lrelu(as.z + ad.z)) : 0.f;
        e.w = act ? __expf(lrelu(as.w + ad.w)) : 0.f;
        float4 sm = e;
        #pragma unroll
        for (int off = 1; off < 64; off <<= 1) {
            sm.x += __shfl_xor(sm.x, off);
            sm.y += __shfl_xor(sm.y, off);
            sm.z += __shfl_xor(sm.z, off);
            sm.w += __shfl_xor(sm.w, off);
        }
        if (act) {
            coef[(size_t)0 * Et + j] = e.x / (sm.x + 1e-16f);
            coef[(size_t)1 * Et + j] = e.y / (sm.y + 1e-16f);
            coef[(size_t)2 * Et + j] = e.z / (sm.z + 1e-16f);
            coef[(size_t)3 * Et + j] = e.w / (sm.w + 1e-16f);
        }
    } else {
        float4 sm = make_float4(0.f, 0.f, 0.f, 0.f);
        for (int j = beg + lane; j < end; j += 64) {
            int s = csr_src[j];
            float4 as = ((const float4*)a_src)[s];
            float4 e;
            e.x = __expf(lrelu(as.x + ad.x));
            e.y = __expf(lrelu(as.y + ad.y));
            e.z = __expf(lrelu(as.z + ad.z));
            e.w = __expf(lrelu(as.w + ad.w));
            coef[(size_t)0 * Et + j] = e.x;
            coef[(size_t)1 * Et + j] = e.y;
            coef[(size_t)2 * Et + j] = e.z;
            coef[(size_t)3 * Et + j] = e.w;
            sm.x += e.x; sm.y += e.y; sm.z += e.z; sm.w += e.w;
        }
        #pragma unroll
        for (int off = 1; off < 64; off <<= 1) {
            sm.x += __shfl_xor(sm.x, off);
            sm.y += __shfl_xor(sm.y, off);
            sm.z += __shfl_xor(sm.z, off);
            sm.w += __shfl_xor(sm.w, off);
        }
        float4 inv;
        inv.x = 1.f / (sm.x + 1e-16f); inv.y = 1.f / (sm.y + 1e-16f);
        inv.z = 1.f / (sm.z + 1e-16f); inv.w = 1.f / (sm.w + 1e-16f);
        for (int j = beg + lane; j < end; j += 64) {
            coef[(size_t)0 * Et + j] *= inv.x;
            coef[(size_t)1 * Et + j] *= inv.y;
            coef[(size_t)2 * Et + j] *= inv.z;
            coef[(size_t)3 * Et + j] *= inv.w;
        }
    }
}

// ---------------- agg: one wave per (dst, slice); 4 edge-slots x 16 ch ----------
// slice = blockIdx%8 -> XCD affinity. Branchless per-lane edge loop: 4 independent
// gather chains in flight per wave. Fused relu(+b1)*W2 reduction -> atomicAdd xw2.
__global__ __launch_bounds__(256) void k_agg(const float* __restrict__ xw,
                                             const float* __restrict__ coef,
                                             const int* __restrict__ row_ptr,
                                             const int* __restrict__ csr_src,
                                             const float* __restrict__ b1,
                                             const float* __restrict__ W2,
                                             float* __restrict__ xw2, int N, int Et)
{
    const int slice = blockIdx.x & 7;
    const int dgrp  = blockIdx.x >> 3;
    const int wave  = threadIdx.x >> 6;
    const int lane  = threadIdx.x & 63;
    const int sub   = lane >> 4, ci = lane & 15;
    const int d     = dgrp * 4 + wave;
    if (d >= N) return;
    const float* xs = xw + (size_t)slice * N * 16;
    const float* ch = coef + (size_t)(slice >> 1) * Et;

    const int beg = row_ptr[d];
    const int deg = row_ptr[d + 1] - beg;
    float acc = 0.f;
    #pragma unroll 2
    for (int k = sub; k < deg; k += 4) {
        int j = beg + k;
        int s = csr_src[j];
        float c = ch[j];
        acc = fmaf(c, xs[(size_t)s * 16 + ci], acc);
    }
    acc += __shfl_xor(acc, 16);
    acc += __shfl_xor(acc, 32);
    int c0 = slice * 16 + ci;
    float t = fmaxf(acc + b1[c0], 0.f) * W2[c0];
    #pragma unroll
    for (int off = 1; off < 16; off <<= 1) t += __shfl_xor(t, off);
    if (lane == 0) atomicAdd(&xw2[d], t);
}

// ---------------- layer 2: scalar GAT head, no max-subtraction ----------------
__global__ __launch_bounds__(256) void k_layer2(const float* __restrict__ xw2,
                                                const int* __restrict__ row_ptr,
                                                const int* __restrict__ csr_src,
                                                const float* __restrict__ att_src2,
                                                const float* __restrict__ att_dst2,
                                                const float* __restrict__ b2,
                                                float* __restrict__ out, int N)
{
    int d = (blockIdx.x * blockDim.x + threadIdx.x) >> 6;
    int lane = threadIdx.x & 63;
    if (d >= N) return;
    float as2 = att_src2[0];
    float adst = xw2[d] * att_dst2[0];
    float l = 0.f, acc = 0.f;
    int beg = row_ptr[d], end = row_ptr[d + 1];
    for (int j = beg + lane; j < end; j += 64) {
        int s = csr_src[j];
        float xs = xw2[s];
        float p = __expf(lrelu(fmaf(xs, as2, adst)));
        l += p;
        acc = fmaf(p, xs, acc);
    }
    #pragma unroll
    for (int off = 1; off < 64; off <<= 1) {
        l   += __shfl_xor(l, off);
        acc += __shfl_xor(acc, off);
    }
    if (lane == 0) out[d] = acc / (l + 1e-16f) + b2[0];
}

extern "C" void kernel_launch(void* const* d_in, const int* in_sizes, int n_in,
                              void* d_out, int out_size, void* d_ws, size_t ws_size,
                              hipStream_t stream)
{
    const float* x        = (const float*)d_in[0];
    const int*   ei       = (const int*)d_in[1];
    const float* W1       = (const float*)d_in[2];
    const float* att_src1 = (const float*)d_in[3];
    const float* att_dst1 = (const float*)d_in[4];
    const float* b1       = (const float*)d_in[5];
    const float* W2       = (const float*)d_in[6];
    const float* att_src2 = (const float*)d_in[7];
    const float* att_dst2 = (const float*)d_in[8];
    const float* b2       = (const float*)d_in[9];
    float* out = (float*)d_out;

    const int N  = in_sizes[0] / 128;
    const int E  = in_sizes[1] / 2;
    const int Et = E + N;

    char* p = (char*)d_ws;
    auto alloc = [&](size_t bytes) {
        char* r = p;
        p += (bytes + 255) & ~(size_t)255;
        return (void*)r;
    };
    float* xw      = (float*)alloc((size_t)N * 128 * 4);   // slice-major [8][N][16]
    float* a_src   = (float*)alloc((size_t)N * 4 * 4);
    float* a_dst   = (float*)alloc((size_t)N * 4 * 4);
    float* xw2     = (float*)alloc((size_t)N * 4);
    int*   deg     = (int*)alloc((size_t)N * 4);
    int*   row_ptr = (int*)alloc((size_t)(N + 1) * 4);
    int*   cursor  = (int*)alloc((size_t)N * 4);
    int*   csr_src = (int*)alloc((size_t)Et * 4);
    float* coef    = (float*)alloc((size_t)Et * 4 * 4);    // HEAD-MAJOR [4][Et]

    hipMemsetAsync(deg, 0, (size_t)N * 4, stream);
    hipMemsetAsync(xw2, 0, (size_t)N * 4, stream);

    k_gemm1  <<<(N + 63) / 64,    256,  0, stream>>>(x, W1, xw, N);
    k_att1   <<<(N + 3) / 4,      256,  0, stream>>>(xw, att_src1, att_dst1, a_src, a_dst, N);
    k_count  <<<(Et + 255) / 256, 256,  0, stream>>>(ei, E, N, deg);
    k_scan   <<<1,                1024, 0, stream>>>(deg, row_ptr, cursor, N);
    k_scatter<<<(Et + 255) / 256, 256,  0, stream>>>(ei, E, N, cursor, csr_src);
    k_coef   <<<(N + 3) / 4,      256,  0, stream>>>(a_src, a_dst, row_ptr, csr_src,
                                                     coef, N, Et);
    k_agg    <<<((N + 3) / 4) * 8, 256, 0, stream>>>(xw, coef, row_ptr, csr_src,
                                                     b1, W2, xw2, N, Et);
    k_layer2 <<<(N + 3) / 4,      256,  0, stream>>>(xw2, row_ptr, csr_src, att_src2,
                                                     att_dst2, b2, out, N);
}

// Round 5
// 587.139 us; speedup vs baseline: 1.2756x; 1.0595x over previous
//
#include <hip/hip_runtime.h>
#include <hip/hip_bf16.h>
#include <cstdint>
#include <cstddef>
#include <math.h>

#define NEG_SLOPE 0.2f

__device__ __forceinline__ float lrelu(float x) { return x > 0.f ? x : NEG_SLOPE * x; }

// Layouts:
//  xw  slice-major [8][N][16] (slice = ch>>4): k_agg pins slice->XCD (blockIdx%8),
//      per-XCD gather working set 3.2 MB < 4 MB L2.
//  pk  head-major planes [4][Et] of packed {src:int, e:float} (8B): one dwordx2
//      per edge in k_agg instead of two dword loads (csr + coef).
//  Softmax normalization is deferred to k_agg's epilogue (linear), so no coef
//  pass exists; k_scatter computes unnormalized e = exp(lrelu(a_src+a_dst)).
//  No max-subtraction: |alpha| <~ 6 here, exp safe in fp32, ratio identical.

// ---------------- GEMM: xw = x @ W1^T (slice-major) + fused a_src/a_dst ----------
__global__ __launch_bounds__(256) void k_gemm1(const float* __restrict__ x,
                                               const float* __restrict__ W1,
                                               const float* __restrict__ att_src,
                                               const float* __restrict__ att_dst,
                                               float* __restrict__ xw,
                                               float* __restrict__ a_src,
                                               float* __restrict__ a_dst, int N)
{
    __shared__ float As[64][33];
    __shared__ float Bs[128][33];
    const int tid = threadIdx.x;
    const int tx = tid & 31, ty = tid >> 5;
    const int bm = blockIdx.x * 64;
    float acc[8][4];
    #pragma unroll
    for (int i = 0; i < 8; i++)
        #pragma unroll
        for (int j = 0; j < 4; j++) acc[i][j] = 0.f;

    for (int k0 = 0; k0 < 128; k0 += 32) {
        #pragma unroll
        for (int t = tid; t < 512; t += 256) {
            int r = t >> 3, q = t & 7;
            int n = bm + r;
            float4 f = make_float4(0.f, 0.f, 0.f, 0.f);
            if (n < N) f = *(const float4*)(x + (size_t)n * 128 + k0 + 4 * q);
            As[r][4*q+0] = f.x; As[r][4*q+1] = f.y; As[r][4*q+2] = f.z; As[r][4*q+3] = f.w;
        }
        #pragma unroll
        for (int t = tid; t < 1024; t += 256) {
            int c = t >> 3, q = t & 7;
            float4 f = *(const float4*)(W1 + (size_t)c * 128 + k0 + 4 * q);
            Bs[c][4*q+0] = f.x; Bs[c][4*q+1] = f.y; Bs[c][4*q+2] = f.z; Bs[c][4*q+3] = f.w;
        }
        __syncthreads();
        #pragma unroll 4
        for (int kk = 0; kk < 32; kk++) {
            float a[8], b[4];
            #pragma unroll
            for (int i = 0; i < 8; i++) a[i] = As[ty * 8 + i][kk];
            #pragma unroll
            for (int j = 0; j < 4; j++) b[j] = Bs[tx + 32 * j][kk];
            #pragma unroll
            for (int i = 0; i < 8; i++)
                #pragma unroll
                for (int j = 0; j < 4; j++) acc[i][j] = fmaf(a[i], b[j], acc[i][j]);
        }
        __syncthreads();
    }

    // att vectors for my 4 channels (ch = tx+32j -> head j, since head = ch>>5)
    float asv[4], adv[4];
    #pragma unroll
    for (int j = 0; j < 4; j++) { asv[j] = att_src[tx + 32 * j]; adv[j] = att_dst[tx + 32 * j]; }

    #pragma unroll
    for (int i = 0; i < 8; i++) {
        int n = bm + ty * 8 + i;
        float sv[4], dv[4];
        #pragma unroll
        for (int j = 0; j < 4; j++) { sv[j] = acc[i][j] * asv[j]; dv[j] = acc[i][j] * adv[j]; }
        #pragma unroll
        for (int off = 1; off < 32; off <<= 1) {   // reduce over tx (stays in 32-lane half)
            #pragma unroll
            for (int j = 0; j < 4; j++) {
                sv[j] += __shfl_xor(sv[j], off);
                dv[j] += __shfl_xor(dv[j], off);
            }
        }
        if (n < N) {
            if (tx == 0) {
                ((float4*)a_src)[n] = make_float4(sv[0], sv[1], sv[2], sv[3]);
                ((float4*)a_dst)[n] = make_float4(dv[0], dv[1], dv[2], dv[3]);
            }
            #pragma unroll
            for (int j = 0; j < 4; j++) {
                int ch = tx + 32 * j;
                xw[((size_t)(ch >> 4) * N + n) * 16 + (ch & 15)] = acc[i][j];
            }
        }
    }
}

// ---------------- CSR build ----------------
__global__ void k_count(const int* __restrict__ ei, int E, int N, int* __restrict__ deg)
{
    int e = blockIdx.x * blockDim.x + threadIdx.x;
    if (e >= E + N) return;
    int d = (e < E) ? ei[(size_t)E + e] : (e - E);
    atomicAdd(&deg[d], 1);
}

__global__ __launch_bounds__(1024) void k_scan(const int* __restrict__ deg,
                                               int* __restrict__ row_ptr,
                                               int* __restrict__ cursor, int N)
{
    __shared__ int wtot[16];
    __shared__ int s_carry;
    const int tid = threadIdx.x;
    const int w = tid >> 6, lane = tid & 63;
    if (tid == 0) s_carry = 0;
    __syncthreads();
    for (int base = 0; base < N; base += 4096) {
        int idx = base + tid * 4;
        int v0 = (idx     < N) ? deg[idx]     : 0;
        int v1 = (idx + 1 < N) ? deg[idx + 1] : 0;
        int v2 = (idx + 2 < N) ? deg[idx + 2] : 0;
        int v3 = (idx + 3 < N) ? deg[idx + 3] : 0;
        int tsum = v0 + v1 + v2 + v3;
        int v = tsum;
        #pragma unroll
        for (int off = 1; off < 64; off <<= 1) {
            int u = __shfl_up(v, off);
            if (lane >= off) v += u;
        }
        if (lane == 63) wtot[w] = v;
        __syncthreads();
        int carry = s_carry;
        if (w == 0) {
            int t = (lane < 16) ? wtot[lane] : 0;
            #pragma unroll
            for (int off = 1; off < 16; off <<= 1) {
                int u = __shfl_up(t, off);
                if (lane >= off) t += u;
            }
            if (lane < 16) wtot[lane] = t;
        }
        __syncthreads();
        int woff = (w > 0) ? wtot[w - 1] : 0;
        int excl = carry + woff + (v - tsum);
        if (idx     < N) { row_ptr[idx]     = excl; cursor[idx]     = excl; } excl += v0;
        if (idx + 1 < N) { row_ptr[idx + 1] = excl; cursor[idx + 1] = excl; } excl += v1;
        if (idx + 2 < N) { row_ptr[idx + 2] = excl; cursor[idx + 2] = excl; } excl += v2;
        if (idx + 3 < N) { row_ptr[idx + 3] = excl; cursor[idx + 3] = excl; }
        __syncthreads();
        if (tid == 0) s_carry = carry + wtot[15];
        __syncthreads();
    }
    if (tid == 0) row_ptr[N] = s_carry;
}

// ---------------- scatter + per-edge unnormalized softmax weights ----------------
// Writes packed {s, e_h} into 4 head-major planes pk[h][Et].
__global__ void k_scatter(const int* __restrict__ ei, int E, int N,
                          int* __restrict__ cursor,
                          const float* __restrict__ a_src,
                          const float* __restrict__ a_dst,
                          uint2* __restrict__ pk, int Et)
{
    int e = blockIdx.x * blockDim.x + threadIdx.x;
    if (e >= Et) return;
    int s, d;
    if (e < E) { s = ei[e]; d = ei[(size_t)E + e]; }
    else       { s = d = e - E; }
    int pos = atomicAdd(&cursor[d], 1);
    float4 as = ((const float4*)a_src)[s];
    float4 ad = ((const float4*)a_dst)[d];
    unsigned us = (unsigned)s;
    pk[(size_t)0 * Et + pos] = make_uint2(us, __float_as_uint(__expf(lrelu(as.x + ad.x))));
    pk[(size_t)1 * Et + pos] = make_uint2(us, __float_as_uint(__expf(lrelu(as.y + ad.y))));
    pk[(size_t)2 * Et + pos] = make_uint2(us, __float_as_uint(__expf(lrelu(as.z + ad.z))));
    pk[(size_t)3 * Et + pos] = make_uint2(us, __float_as_uint(__expf(lrelu(as.w + ad.w))));
}

// ---------------- agg: one wave per (dst, slice); 4 edge-slots x 16 ch ----------
// One dwordx2 per edge-slot; denom accumulated inline; normalize in epilogue.
// Fused relu(+b1)*W2 reduction -> atomicAdd xw2.
__global__ __launch_bounds__(256) void k_agg(const float* __restrict__ xw,
                                             const uint2* __restrict__ pk,
                                             const int* __restrict__ row_ptr,
                                             const float* __restrict__ b1,
                                             const float* __restrict__ W2,
                                             float* __restrict__ xw2, int N, int Et)
{
    const int slice = blockIdx.x & 7;
    const int dgrp  = blockIdx.x >> 3;
    const int wave  = threadIdx.x >> 6;
    const int lane  = threadIdx.x & 63;
    const int sub   = lane >> 4, ci = lane & 15;
    const int d     = dgrp * 4 + wave;
    if (d >= N) return;
    const float* xs = xw + (size_t)slice * N * 16;
    const uint2* ph = pk + (size_t)(slice >> 1) * Et;

    const int beg = row_ptr[d];
    const int deg = row_ptr[d + 1] - beg;
    float acc = 0.f, csum = 0.f;
    #pragma unroll 4
    for (int k = sub; k < deg; k += 4) {
        uint2 p = ph[beg + k];
        int s = (int)p.x;
        float c = __uint_as_float(p.y);
        acc = fmaf(c, xs[(size_t)s * 16 + ci], acc);
        csum += c;
    }
    acc  += __shfl_xor(acc, 16);  acc  += __shfl_xor(acc, 32);
    csum += __shfl_xor(csum, 16); csum += __shfl_xor(csum, 32);
    int c0 = slice * 16 + ci;
    float t = fmaxf(acc / (csum + 1e-16f) + b1[c0], 0.f) * W2[c0];
    #pragma unroll
    for (int off = 1; off < 16; off <<= 1) t += __shfl_xor(t, off);
    if (lane == 0) atomicAdd(&xw2[d], t);
}

// ---------------- layer 2: scalar GAT head (src indices from pk plane 0) --------
__global__ __launch_bounds__(256) void k_layer2(const float* __restrict__ xw2,
                                                const int* __restrict__ row_ptr,
                                                const uint2* __restrict__ pk0,
                                                const float* __restrict__ att_src2,
                                                const float* __restrict__ att_dst2,
                                                const float* __restrict__ b2,
                                                float* __restrict__ out, int N)
{
    int d = (blockIdx.x * blockDim.x + threadIdx.x) >> 6;
    int lane = threadIdx.x & 63;
    if (d >= N) return;
    float as2 = att_src2[0];
    float adst = xw2[d] * att_dst2[0];
    float l = 0.f, acc = 0.f;
    int beg = row_ptr[d], end = row_ptr[d + 1];
    for (int j = beg + lane; j < end; j += 64) {
        int s = (int)pk0[j].x;
        float xs = xw2[s];
        float p = __expf(lrelu(fmaf(xs, as2, adst)));
        l += p;
        acc = fmaf(p, xs, acc);
    }
    #pragma unroll
    for (int off = 1; off < 64; off <<= 1) {
        l   += __shfl_xor(l, off);
        acc += __shfl_xor(acc, off);
    }
    if (lane == 0) out[d] = acc / (l + 1e-16f) + b2[0];
}

extern "C" void kernel_launch(void* const* d_in, const int* in_sizes, int n_in,
                              void* d_out, int out_size, void* d_ws, size_t ws_size,
                              hipStream_t stream)
{
    const float* x        = (const float*)d_in[0];
    const int*   ei       = (const int*)d_in[1];
    const float* W1       = (const float*)d_in[2];
    const float* att_src1 = (const float*)d_in[3];
    const float* att_dst1 = (const float*)d_in[4];
    const float* b1       = (const float*)d_in[5];
    const float* W2       = (const float*)d_in[6];
    const float* att_src2 = (const float*)d_in[7];
    const float* att_dst2 = (const float*)d_in[8];
    const float* b2       = (const float*)d_in[9];
    float* out = (float*)d_out;

    const int N  = in_sizes[0] / 128;
    const int E  = in_sizes[1] / 2;
    const int Et = E + N;

    char* p = (char*)d_ws;
    auto alloc = [&](size_t bytes) {
        char* r = p;
        p += (bytes + 255) & ~(size_t)255;
        return (void*)r;
    };
    float* xw      = (float*)alloc((size_t)N * 128 * 4);   // slice-major [8][N][16]
    float* a_src   = (float*)alloc((size_t)N * 4 * 4);
    float* a_dst   = (float*)alloc((size_t)N * 4 * 4);
    float* xw2     = (float*)alloc((size_t)N * 4);
    int*   deg     = (int*)alloc((size_t)N * 4);
    int*   row_ptr = (int*)alloc((size_t)(N + 1) * 4);
    int*   cursor  = (int*)alloc((size_t)N * 4);
    uint2* pk      = (uint2*)alloc((size_t)4 * Et * 8);    // [4][Et] packed {s, e_h}

    hipMemsetAsync(deg, 0, (size_t)N * 4, stream);
    hipMemsetAsync(xw2, 0, (size_t)N * 4, stream);

    k_gemm1  <<<(N + 63) / 64,    256,  0, stream>>>(x, W1, att_src1, att_dst1,
                                                     xw, a_src, a_dst, N);
    k_count  <<<(Et + 255) / 256, 256,  0, stream>>>(ei, E, N, deg);
    k_scan   <<<1,                1024, 0, stream>>>(deg, row_ptr, cursor, N);
    k_scatter<<<(Et + 255) / 256, 256,  0, stream>>>(ei, E, N, cursor, a_src, a_dst,
                                                     pk, Et);
    k_agg    <<<((N + 3) / 4) * 8, 256, 0, stream>>>(xw, pk, row_ptr, b1, W2, xw2, N, Et);
    k_layer2 <<<(N + 3) / 4,      256,  0, stream>>>(xw2, row_ptr, pk, att_src2,
                                                     att_dst2, b2, out, N);
}

// Round 6
// 473.688 us; speedup vs baseline: 1.5812x; 1.2395x over previous
//
#include <hip/hip_runtime.h>
#include <hip/hip_bf16.h>
#include <cstdint>
#include <cstddef>
#include <math.h>

#define NEG_SLOPE 0.2f

__device__ __forceinline__ float lrelu(float x) { return x > 0.f ? x : NEG_SLOPE * x; }

// Layouts:
//  xw  slice-major [8][N][16] (slice = ch>>4): k_agg pins slice->XCD (blockIdx%8),
//      per-XCD gather working set 3.2 MB < 4 MB L2 (verified: FETCH 320->70 MB r4).
//  pk  head-major planes [4][Et] of packed {src:int, e:float} (8B): one dwordx2
//      per edge-quad in k_agg.
//  Softmax normalization deferred to k_agg epilogue (linear); k_scatter computes
//  unnormalized e = exp(lrelu(a_src+a_dst)). No max-subtraction (|alpha|<~6, fp32-safe).
//  k_agg r6: 4 lanes/edge x float4 channels (16 edge-slots/wave) - 4x less issue
//  per edge than r5's 16 lanes/edge x 1 channel.

// ---------------- GEMM: xw = x @ W1^T (slice-major) + fused a_src/a_dst ----------
// k-major LDS tiles so the inner loop is 3x ds_read_b128 per 32 fmas.
__global__ __launch_bounds__(256) void k_gemm1(const float* __restrict__ x,
                                               const float* __restrict__ W1,
                                               const float* __restrict__ att_src,
                                               const float* __restrict__ att_dst,
                                               float* __restrict__ xw,
                                               float* __restrict__ a_src,
                                               float* __restrict__ a_dst, int N)
{
    __shared__ float As[32 * 68];    // As[kk*68 + r], r<64   (68*4B: 16B-aligned rows)
    __shared__ float Bs[32 * 132];   // Bs[kk*132 + c], c<128 (132*4B: 16B-aligned rows)
    const int tid = threadIdx.x;
    const int tx = tid & 31, ty = tid >> 5;
    const int bm = blockIdx.x * 64;
    float acc[8][4] = {};

    for (int k0 = 0; k0 < 128; k0 += 32) {
        #pragma unroll
        for (int t = tid; t < 512; t += 256) {          // A tile 64 rows x 32 k
            int r = t >> 3, q = t & 7;
            int n = bm + r;
            float4 f = make_float4(0.f, 0.f, 0.f, 0.f);
            if (n < N) f = *(const float4*)(x + (size_t)n * 128 + k0 + 4 * q);
            As[(4*q+0)*68 + r] = f.x; As[(4*q+1)*68 + r] = f.y;
            As[(4*q+2)*68 + r] = f.z; As[(4*q+3)*68 + r] = f.w;
        }
        #pragma unroll
        for (int t = tid; t < 1024; t += 256) {         // B tile 128 cols x 32 k
            int c = t >> 3, q = t & 7;
            float4 f = *(const float4*)(W1 + (size_t)c * 128 + k0 + 4 * q);
            Bs[(4*q+0)*132 + c] = f.x; Bs[(4*q+1)*132 + c] = f.y;
            Bs[(4*q+2)*132 + c] = f.z; Bs[(4*q+3)*132 + c] = f.w;
        }
        __syncthreads();
        #pragma unroll 8
        for (int kk = 0; kk < 32; kk++) {
            float4 a0 = *(const float4*)&As[kk * 68 + ty * 8];
            float4 a1 = *(const float4*)&As[kk * 68 + ty * 8 + 4];
            float4 b4 = *(const float4*)&Bs[kk * 132 + tx * 4];
            float a[8] = {a0.x, a0.y, a0.z, a0.w, a1.x, a1.y, a1.z, a1.w};
            float b[4] = {b4.x, b4.y, b4.z, b4.w};
            #pragma unroll
            for (int i = 0; i < 8; i++)
                #pragma unroll
                for (int j = 0; j < 4; j++) acc[i][j] = fmaf(a[i], b[j], acc[i][j]);
        }
        __syncthreads();
    }

    // thread owns cols ch = tx*4+j (contiguous) -> slice = tx>>2, head = tx>>3
    float asv[4], adv[4];
    #pragma unroll
    for (int j = 0; j < 4; j++) { asv[j] = att_src[tx*4+j]; adv[j] = att_dst[tx*4+j]; }
    const int slice = tx >> 2, cio = (tx & 3) * 4, head = tx >> 3;

    #pragma unroll
    for (int i = 0; i < 8; i++) {
        int n = bm + ty * 8 + i;
        float sv = 0.f, dv = 0.f;
        #pragma unroll
        for (int j = 0; j < 4; j++) {
            sv = fmaf(acc[i][j], asv[j], sv);
            dv = fmaf(acc[i][j], adv[j], dv);
        }
        #pragma unroll
        for (int off = 1; off < 8; off <<= 1) {          // reduce 8 lanes of one head
            sv += __shfl_xor(sv, off);
            dv += __shfl_xor(dv, off);
        }
        if (n < N) {
            *(float4*)&xw[((size_t)slice * N + n) * 16 + cio] =
                make_float4(acc[i][0], acc[i][1], acc[i][2], acc[i][3]);
            if ((tx & 7) == 0) {
                a_src[n * 4 + head] = sv;
                a_dst[n * 4 + head] = dv;
            }
        }
    }
}

// ---------------- CSR build ----------------
__global__ void k_count(const int* __restrict__ ei, int E, int N, int* __restrict__ deg)
{
    int e = blockIdx.x * blockDim.x + threadIdx.x;
    if (e >= E + N) return;
    int d = (e < E) ? ei[(size_t)E + e] : (e - E);
    atomicAdd(&deg[d], 1);
}

// two-level scan: A) per-block sums  B) 64-lane scan of partials  C) local scans
__global__ __launch_bounds__(1024) void k_scanA(const int* __restrict__ deg,
                                                int* __restrict__ partial, int N, int R)
{
    __shared__ int ws[16];
    const int b = blockIdx.x, tid = threadIdx.x, w = tid >> 6, lane = tid & 63;
    int endi = (b + 1) * R; if (endi > N) endi = N;
    int s = 0;
    for (int i = b * R + tid; i < endi; i += 1024) s += deg[i];
    #pragma unroll
    for (int off = 1; off < 64; off <<= 1) s += __shfl_xor(s, off);
    if (lane == 0) ws[w] = s;
    __syncthreads();
    if (tid == 0) {
        int t = 0;
        #pragma unroll
        for (int i = 0; i < 16; i++) t += ws[i];
        partial[b] = t;
    }
}

__global__ void k_scanB(int* __restrict__ partial, int nblk,
                        int* __restrict__ row_ptr, int N)
{
    int lane = threadIdx.x;                      // 64 threads
    int orig = (lane < nblk) ? partial[lane] : 0;
    int v = orig;
    #pragma unroll
    for (int off = 1; off < 64; off <<= 1) {
        int u = __shfl_up(v, off);
        if (lane >= off) v += u;
    }
    if (lane < nblk) partial[lane] = v - orig;   // exclusive
    if (lane == 63) row_ptr[N] = v;              // total
}

__global__ __launch_bounds__(1024) void k_scanC(const int* __restrict__ deg,
                                                const int* __restrict__ partial,
                                                int* __restrict__ row_ptr,
                                                int* __restrict__ cursor, int N, int R)
{
    __shared__ int wtot[16];
    __shared__ int s_carry;
    const int b = blockIdx.x, tid = threadIdx.x, w = tid >> 6, lane = tid & 63;
    if (tid == 0) s_carry = partial[b];
    __syncthreads();
    for (int off0 = 0; off0 < R; off0 += 1024) {
        int idx = b * R + off0 + tid;
        int v0 = (idx < N) ? deg[idx] : 0;
        int v = v0;
        #pragma unroll
        for (int off = 1; off < 64; off <<= 1) {
            int u = __shfl_up(v, off);
            if (lane >= off) v += u;
        }
        if (lane == 63) wtot[w] = v;
        __syncthreads();
        int carry = s_carry;
        if (w == 0) {
            int t = (lane < 16) ? wtot[lane] : 0;
            #pragma unroll
            for (int off = 1; off < 16; off <<= 1) {
                int u = __shfl_up(t, off);
                if (lane >= off) t += u;
            }
            if (lane < 16) wtot[lane] = t;
        }
        __syncthreads();
        int woff = (w > 0) ? wtot[w - 1] : 0;
        int excl = carry + woff + (v - v0);
        if (idx < N) { row_ptr[idx] = excl; cursor[idx] = excl; }
        __syncthreads();
        if (tid == 0) s_carry = carry + wtot[15];
        __syncthreads();
    }
}

// ---------------- scatter + per-edge unnormalized softmax weights ----------------
__global__ void k_scatter(const int* __restrict__ ei, int E, int N,
                          int* __restrict__ cursor,
                          const float* __restrict__ a_src,
                          const float* __restrict__ a_dst,
                          uint2* __restrict__ pk, int Et)
{
    int e = blockIdx.x * blockDim.x + threadIdx.x;
    if (e >= Et) return;
    int s, d;
    if (e < E) { s = ei[e]; d = ei[(size_t)E + e]; }
    else       { s = d = e - E; }
    int pos = atomicAdd(&cursor[d], 1);
    float4 as = ((const float4*)a_src)[s];
    float4 ad = ((const float4*)a_dst)[d];
    unsigned us = (unsigned)s;
    pk[(size_t)0 * Et + pos] = make_uint2(us, __float_as_uint(__expf(lrelu(as.x + ad.x))));
    pk[(size_t)1 * Et + pos] = make_uint2(us, __float_as_uint(__expf(lrelu(as.y + ad.y))));
    pk[(size_t)2 * Et + pos] = make_uint2(us, __float_as_uint(__expf(lrelu(as.z + ad.z))));
    pk[(size_t)3 * Et + pos] = make_uint2(us, __float_as_uint(__expf(lrelu(as.w + ad.w))));
}

// ---------------- agg: one wave per (dst, slice); 16 edge-slots x 4 lanes/edge ---
// Each lane: float4 of channels. One uint2 per edge-quad. Denominator accumulated
// inline; normalize + relu(+b1)*W2 reduction -> atomicAdd xw2 in epilogue.
__global__ __launch_bounds__(256) void k_agg(const float* __restrict__ xw,
                                             const uint2* __restrict__ pk,
                                             const int* __restrict__ row_ptr,
                                             const float* __restrict__ b1,
                                             const float* __restrict__ W2,
                                             float* __restrict__ xw2, int N, int Et)
{
    const int slice = blockIdx.x & 7;
    const int dgrp  = blockIdx.x >> 3;
    const int wave  = threadIdx.x >> 6;
    const int lane  = threadIdx.x & 63;
    const int slot  = lane >> 2, li = lane & 3;       // 16 edge-slots x 4 ch-lanes
    const int d     = dgrp * 4 + wave;
    if (d >= N) return;
    const float4* xs4 = (const float4*)(xw + (size_t)slice * N * 16);
    const uint2*  ph  = pk + (size_t)(slice >> 1) * Et;

    const int beg = row_ptr[d];
    const int deg = row_ptr[d + 1] - beg;
    float4 acc = make_float4(0.f, 0.f, 0.f, 0.f);
    float csum = 0.f;
    #pragma unroll 2
    for (int k = slot; k < deg; k += 16) {
        uint2 p = ph[beg + k];
        float c = __uint_as_float(p.y);
        float4 v = xs4[(size_t)p.x * 4 + li];
        acc.x = fmaf(c, v.x, acc.x);
        acc.y = fmaf(c, v.y, acc.y);
        acc.z = fmaf(c, v.z, acc.z);
        acc.w = fmaf(c, v.w, acc.w);
        csum += c;
    }
    #pragma unroll
    for (int off = 4; off < 64; off <<= 1) {          // reduce over slots (bits 2..5)
        acc.x += __shfl_xor(acc.x, off);
        acc.y += __shfl_xor(acc.y, off);
        acc.z += __shfl_xor(acc.z, off);
        acc.w += __shfl_xor(acc.w, off);
        csum  += __shfl_xor(csum, off);
    }
    float4 bb = ((const float4*)b1)[slice * 4 + li];
    float4 ww = ((const float4*)W2)[slice * 4 + li];
    float inv = 1.f / (csum + 1e-16f);
    float t = fmaxf(fmaf(acc.x, inv, bb.x), 0.f) * ww.x
            + fmaxf(fmaf(acc.y, inv, bb.y), 0.f) * ww.y
            + fmaxf(fmaf(acc.z, inv, bb.z), 0.f) * ww.z
            + fmaxf(fmaf(acc.w, inv, bb.w), 0.f) * ww.w;
    t += __shfl_xor(t, 1);
    t += __shfl_xor(t, 2);
    if (lane == 0) atomicAdd(&xw2[d], t);
}

// ---------------- layer 2: scalar GAT head (src indices from pk plane 0) --------
__global__ __launch_bounds__(256) void k_layer2(const float* __restrict__ xw2,
                                                const int* __restrict__ row_ptr,
                                                const uint2* __restrict__ pk0,
                                                const float* __restrict__ att_src2,
                                                const float* __restrict__ att_dst2,
                                                const float* __restrict__ b2,
                                                float* __restrict__ out, int N)
{
    int d = (blockIdx.x * blockDim.x + threadIdx.x) >> 6;
    int lane = threadIdx.x & 63;
    if (d >= N) return;
    float as2 = att_src2[0];
    float adst = xw2[d] * att_dst2[0];
    float l = 0.f, acc = 0.f;
    int beg = row_ptr[d], end = row_ptr[d + 1];
    for (int j = beg + lane; j < end; j += 64) {
        int s = (int)pk0[j].x;
        float xs = xw2[s];
        float p = __expf(lrelu(fmaf(xs, as2, adst)));
        l += p;
        acc = fmaf(p, xs, acc);
    }
    #pragma unroll
    for (int off = 1; off < 64; off <<= 1) {
        l   += __shfl_xor(l, off);
        acc += __shfl_xor(acc, off);
    }
    if (lane == 0) out[d] = acc / (l + 1e-16f) + b2[0];
}

extern "C" void kernel_launch(void* const* d_in, const int* in_sizes, int n_in,
                              void* d_out, int out_size, void* d_ws, size_t ws_size,
                              hipStream_t stream)
{
    const float* x        = (const float*)d_in[0];
    const int*   ei       = (const int*)d_in[1];
    const float* W1       = (const float*)d_in[2];
    const float* att_src1 = (const float*)d_in[3];
    const float* att_dst1 = (const float*)d_in[4];
    const float* b1       = (const float*)d_in[5];
    const float* W2       = (const float*)d_in[6];
    const float* att_src2 = (const float*)d_in[7];
    const float* att_dst2 = (const float*)d_in[8];
    const float* b2       = (const float*)d_in[9];
    float* out = (float*)d_out;

    const int N  = in_sizes[0] / 128;
    const int E  = in_sizes[1] / 2;
    const int Et = E + N;

    int R = 1024;                              // scan chunk; nblk <= 64
    while ((N + R - 1) / R > 64) R += 1024;
    const int nblk = (N + R - 1) / R;

    char* p = (char*)d_ws;
    auto alloc = [&](size_t bytes) {
        char* r = p;
        p += (bytes + 255) & ~(size_t)255;
        return (void*)r;
    };
    float* xw      = (float*)alloc((size_t)N * 128 * 4);   // slice-major [8][N][16]
    float* a_src   = (float*)alloc((size_t)N * 4 * 4);
    float* a_dst   = (float*)alloc((size_t)N * 4 * 4);
    float* xw2     = (float*)alloc((size_t)N * 4);
    int*   deg     = (int*)alloc((size_t)N * 4);
    int*   row_ptr = (int*)alloc((size_t)(N + 1) * 4);
    int*   cursor  = (int*)alloc((size_t)N * 4);
    int*   partial = (int*)alloc((size_t)64 * 4);
    uint2* pk      = (uint2*)alloc((size_t)4 * Et * 8);    // [4][Et] packed {s, e_h}

    hipMemsetAsync(deg, 0, (size_t)N * 4, stream);
    hipMemsetAsync(xw2, 0, (size_t)N * 4, stream);

    k_gemm1  <<<(N + 63) / 64,    256,  0, stream>>>(x, W1, att_src1, att_dst1,
                                                     xw, a_src, a_dst, N);
    k_count  <<<(Et + 255) / 256, 256,  0, stream>>>(ei, E, N, deg);
    k_scanA  <<<nblk,             1024, 0, stream>>>(deg, partial, N, R);
    k_scanB  <<<1,                64,   0, stream>>>(partial, nblk, row_ptr, N);
    k_scanC  <<<nblk,             1024, 0, stream>>>(deg, partial, row_ptr, cursor, N, R);
    k_scatter<<<(Et + 255) / 256, 256,  0, stream>>>(ei, E, N, cursor, a_src, a_dst,
                                                     pk, Et);
    k_agg    <<<((N + 3) / 4) * 8, 256, 0, stream>>>(xw, pk, row_ptr, b1, W2, xw2, N, Et);
    k_layer2 <<<(N + 3) / 4,      256,  0, stream>>>(xw2, row_ptr, pk, att_src2,
                                                     att_dst2, b2, out, N);
}